// Round 4
// baseline (955.935 us; speedup 1.0000x reference)
//
#include <hip/hip_runtime.h>

// DiffusionBlock: 20 steps of depthwise 3x3 stencil, reflect padding, on
// (16,2,1024,1024) fp32 — SINGLE launch, all 20 steps fused.
//
// LDS-free register-rolling pipeline (5-point cross stencil: corner weights
// are exactly 0; w_l==w_r, w_t==w_b):
//   u_{s+1}[r] = w01*(u_s[r-1]+u_s[r+1]) + w10*(left+right) + w11*u_s[r]
// Each wave owns a 256-col swath (float4/lane) and marches down rows keeping
// a 2-row register window per fused stage (40 NAMED ext_vector registers —
// never arrays, so scalar replacement is guaranteed; round-1 lesson).
// Horizontal halo via DPP wave_shr:1/wave_shl:1. Column mirror patched by
// per-lane cndmask; row mirror handled exactly in gated head/tail phases.
//
// ROUND 4: identical algorithm to round 3 (which never ran — container died
// twice, suspected compile blow-up from outer-loop unrolling of the huge
// macro bodies). Added `#pragma clang loop unroll(disable)` on the three
// outer row-loops: each body is already a straight-line 20-stage block and
// iterations are serially dependent, so unrolling is pure code-size.

#define IMG  1024
#define KF   20           // fused steps (all of them)
#define RB   64           // output rows per band
#define LPAD 20           // left extension cols (>= KF, multiple of 4)
#define SW   216          // useful cols per swath (256 - 2*LPAD)
#define NSW  5            // 5*216 = 1080 >= 1024
#define NB   (IMG/RB)     // 16 bands
#define NPL  32           // planes = 16 batch * 2 ch
#define WPL  (NB*NSW)     // 80 waves per plane
#define NWAVES (NPL*WPL)  // 2560

typedef float f32x4 __attribute__((ext_vector_type(4)));
typedef float f32x2 __attribute__((ext_vector_type(2)));

__device__ __forceinline__ float dpp_left(float v) {   // lane i <- lane i-1 (wave_shr:1)
    return __int_as_float(__builtin_amdgcn_update_dpp(
        __float_as_int(v), __float_as_int(v), 0x138, 0xf, 0xf, false));
}
__device__ __forceinline__ float dpp_right(float v) {  // lane i <- lane i+1 (wave_shl:1)
    return __int_as_float(__builtin_amdgcn_update_dpp(
        __float_as_int(v), __float_as_int(v), 0x130, 0xf, 0xf, false));
}

// One fused stage: consumes C (= u_{j-1}[f+1]), bank OV (= u_{j-1}[f-1]),
// bank NV (= u_{j-1}[f]); produces u_j[f] into C, rotates OV <- old C.
// GEN=1 adds uniform activity gating + row-mirror patches (head/tail only).
#define STAGE(jj, OV, NV, GEN)                                               \
    {                                                                        \
        f32x4 Cn; bool pr = true;                                            \
        const int f = _r - (jj);                                             \
        bool act = true;                                                     \
        if (GEN) {                                                           \
            const int lo = max(ob - KF + (jj), 0);                           \
            const int hi = min(ob + RB - 1 + KF - (jj), IMG - 1);            \
            act = (f >= lo) && (f <= hi);                                    \
        }                                                                    \
        if (act) {                                                           \
            const f32x4 mid = NV;                                            \
            f32x4 vs;                                                        \
            if (GEN && f == 0)              vs = C + C;    /* u[-1]=u[1] */  \
            else if (GEN && f == IMG - 1)   vs = OV + OV;  /* u[N]=u[N-2] */ \
            else                            vs = OV + C;                     \
            float lf = dpp_left(mid.w);                                      \
            float rg = dpp_right(mid.x);                                     \
            if (is_cL) lf = mid.y;             /* col 0: mirror col 1 */     \
            if (is_cR) rg = mid.z;             /* col 1023: mirror 1022 */   \
            f32x2 hlo, hhi;                                                  \
            hlo.x = lf    + mid.y;  hlo.y = mid.x + mid.z;                   \
            hhi.x = mid.y + mid.w;  hhi.y = mid.z + rg;                      \
            Cn.lo = vs.lo * w01 + hlo * w10 + mid.lo * w11;                  \
            Cn.hi = vs.hi * w01 + hhi * w10 + mid.hi * w11;                  \
        } else { pr = false; Cn = C; }                                       \
        if (prod) { OV = C; }                                                \
        C = Cn; prod = GEN ? pr : true;                                      \
    }

// One pipeline advance at absolute input row rv. PF (p0/p1) holds row rv,
// reloaded with row rv+2. Bank names passed explicitly per stage.
#define STEPN(rv, PF, GEN,                                                   \
              O0,N0,O1,N1,O2,N2,O3,N3,O4,N4,O5,N5,O6,N6,O7,N7,O8,N8,O9,N9,  \
              O10,N10,O11,N11,O12,N12,O13,N13,O14,N14,O15,N15,O16,N16,      \
              O17,N17,O18,N18,O19,N19)                                       \
    do {                                                                     \
        const int _r = (rv);                                                 \
        f32x4 C = PF;                                                        \
        if (_r + 2 <= in_hi)                                                 \
            PF = *(const f32x4*)(lp + (size_t)(_r + 2) * IMG);               \
        bool prod = GEN ? (_r <= in_hi) : true;                              \
        STAGE(1,  O0,  N0,  GEN)                                             \
        STAGE(2,  O1,  N1,  GEN)                                             \
        STAGE(3,  O2,  N2,  GEN)                                             \
        STAGE(4,  O3,  N3,  GEN)                                             \
        STAGE(5,  O4,  N4,  GEN)                                             \
        STAGE(6,  O5,  N5,  GEN)                                             \
        STAGE(7,  O6,  N6,  GEN)                                             \
        STAGE(8,  O7,  N7,  GEN)                                             \
        STAGE(9,  O8,  N8,  GEN)                                             \
        STAGE(10, O9,  N9,  GEN)                                             \
        STAGE(11, O10, N10, GEN)                                             \
        STAGE(12, O11, N11, GEN)                                             \
        STAGE(13, O12, N12, GEN)                                             \
        STAGE(14, O13, N13, GEN)                                             \
        STAGE(15, O14, N14, GEN)                                             \
        STAGE(16, O15, N15, GEN)                                             \
        STAGE(17, O16, N16, GEN)                                             \
        STAGE(18, O17, N17, GEN)                                             \
        STAGE(19, O18, N18, GEN)                                             \
        STAGE(20, O19, N19, GEN)                                             \
        if ((!GEN || prod) && st_ok)                                         \
            *(f32x4*)(op + (size_t)(_r - KF) * IMG) = C;                     \
    } while (0)

#define STEP_E(rv, GEN) STEPN(rv, p0, GEN,                                   \
    a0,b0,a1,b1,a2,b2,a3,b3,a4,b4,a5,b5,a6,b6,a7,b7,a8,b8,a9,b9,             \
    a10,b10,a11,b11,a12,b12,a13,b13,a14,b14,a15,b15,a16,b16,a17,b17,         \
    a18,b18,a19,b19)
#define STEP_O(rv, GEN) STEPN(rv, p1, GEN,                                   \
    b0,a0,b1,a1,b2,a2,b3,a3,b4,a4,b5,a5,b6,a6,b7,a7,b8,a8,b9,a9,             \
    b10,a10,b11,a11,b12,a12,b13,a13,b14,a14,b15,a15,b16,a16,b17,a17,         \
    b18,a18,b19,a19)

__global__ __launch_bounds__(64, 2) void diff20(
    const float* __restrict__ src, float* __restrict__ dst,
    const float* __restrict__ wt)
{
    const int lane  = threadIdx.x;          // 64-thread block == one wave
    const int gw    = blockIdx.x;
    const int plane = gw / WPL;
    const int rem   = gw - plane * WPL;
    const int band  = rem / NSW;
    const int sw    = rem - band * NSW;

    const int ob  = band * RB;              // first output row of this band
    const int uc0 = sw * SW;                // first useful col of this swath
    const int c0  = uc0 - LPAD + 4 * lane;  // this lane's first col (may be <0)
    const int cld = min(max(c0, 0), IMG - 4); // clamped load col (garbage ok)

    const float* __restrict__ lp = src + (size_t)plane * IMG * IMG + cld;
    float* __restrict__       op = dst + (size_t)plane * IMG * IMG + cld;

    const float* w9 = wt + (size_t)(plane & 1) * 9;
    const float w01 = w9[1];   // vertical weight (== w9[7])
    const float w10 = w9[3];   // horizontal weight (== w9[5])
    const float w11 = w9[4];   // center weight (corners are 0)

    const bool is_cL  = (c0 == 0);          // lane's .x is image col 0
    const bool is_cR  = (c0 == IMG - 4);    // lane's .w is image col 1023
    const bool st_ok  = (c0 >= uc0) && (c0 < uc0 + SW) && (c0 <= IMG - 4);

    const int r_lo  = max(ob - KF, 0);
    const int in_hi = min(ob + RB - 1 + KF, IMG - 1);
    const int r_hi  = ob + RB - 1 + KF;     // last pipeline iteration
    const int head_end = r_lo + 2 * KF - 1; // generic head (2*KF steps, even)
    const int st_end   = min(r_hi, IMG - 1);// steady end; tail drains

    // 2-row banks for stages u_0..u_19 — NAMED registers (never an array).
    f32x4 a0=0,a1=0,a2=0,a3=0,a4=0,a5=0,a6=0,a7=0,a8=0,a9=0;
    f32x4 a10=0,a11=0,a12=0,a13=0,a14=0,a15=0,a16=0,a17=0,a18=0,a19=0;
    f32x4 b0=0,b1=0,b2=0,b3=0,b4=0,b5=0,b6=0,b7=0,b8=0,b9=0;
    f32x4 b10=0,b11=0,b12=0,b13=0,b14=0,b15=0,b16=0,b17=0,b18=0,b19=0;

    f32x4 p0, p1;                           // distance-2 row prefetch slots
    p0 = *(const f32x4*)(lp + (size_t)r_lo * IMG);
    p1 = *(const f32x4*)(lp + (size_t)(r_lo + 1) * IMG);

    // Phase lengths are even and preserve the even/odd role alternation.
    // unroll(disable): bodies are already ~500-inst straight-line blocks and
    // iterations are serially dependent — unrolling is pure code-size.
    #pragma clang loop unroll(disable)
    for (int r = r_lo; r <= head_end; r += 2) {
        STEP_E(r,     1);
        STEP_O(r + 1, 1);
    }
    #pragma clang loop unroll(disable)
    for (int r = head_end + 1; r <= st_end; r += 2) {
        STEP_E(r,     0);
        STEP_O(r + 1, 0);
    }
    #pragma clang loop unroll(disable)
    for (int r = st_end + 1; r <= r_hi; r += 2) {
        STEP_E(r,     1);
        STEP_O(r + 1, 1);
    }
}

extern "C" void kernel_launch(void* const* d_in, const int* in_sizes, int n_in,
                              void* d_out, int out_size, void* d_ws, size_t ws_size,
                              hipStream_t stream) {
    const float* x  = (const float*)d_in[0];
    const float* wt = (const float*)d_in[1];
    float* out = (float*)d_out;
    (void)d_ws; (void)ws_size;

    dim3 g(NWAVES), b(64);
    // all 20 steps in one launch
    diff20<<<g, b, 0, stream>>>(x, out, wt);
}

// Round 5
// 453.132 us; speedup vs baseline: 2.1096x; 2.1096x over previous
//
#include <hip/hip_runtime.h>

// DiffusionBlock: 20 steps of depthwise 3x3 stencil, reflect padding, on
// (16,2,1024,1024) fp32. Two launches of KF=10 fused steps.
//
// LDS-free register-rolling pipeline (5-point cross stencil: corner weights
// are exactly 0; w_l==w_r, w_t==w_b):
//   u_{s+1}[r] = w01*(u_s[r-1]+u_s[r+1]) + w10*(left+right) + w11*u_s[r]
// Each wave owns a 256-col swath (float4/lane) and marches down rows keeping
// a 2-row register window per fused stage (20 NAMED ext_vector registers —
// never arrays; round-1 lesson: arrays get demoted to scratch).
// Horizontal halo via DPP wave_shr:1/wave_shl:1. Column mirror patched by
// per-lane cndmask; row mirror handled exactly in gated head/tail phases.
//
// ROUND 5: round 4 (KF=20 single launch) re-spilled: 40 live banks is past
// what the allocator holds (VGPR=128 reported, WRITE_SIZE 7.5x = scratch).
// Revert to the proven KF=10 two-launch structure (round 2: VGPR=80, zero
// spill, 132us/dispatch) and keep ONLY the packed-fp32 ext_vector math from
// round 3/4: ISel emits v_pk_add_f32/v_pk_fma_f32 (double-rate fp32), ~24
// scalar ops/stage -> ~16 ops with 8 double-width. Round 2 was VALU-issue
// bound (VALUBusy 63%, HBM 22%), so issue-count is the binding resource.

#define IMG  1024
#define KF   10           // fused steps per launch
#define RB   64           // output rows per band
#define LPAD 12           // left extension cols (>= KF, multiple of 4)
#define SW   232          // useful cols per swath (256 - 2*LPAD + 8... = 232)
#define NSW  5            // 5*232 = 1160 >= 1024
#define NB   (IMG/RB)     // 16 bands
#define NPL  32           // planes = 16 batch * 2 ch
#define WPL  (NB*NSW)     // 80 waves per plane
#define NWAVES (NPL*WPL)  // 2560

typedef float f32x4 __attribute__((ext_vector_type(4)));
typedef float f32x2 __attribute__((ext_vector_type(2)));

__device__ __forceinline__ float dpp_left(float v) {   // lane i <- lane i-1 (wave_shr:1)
    return __int_as_float(__builtin_amdgcn_update_dpp(
        __float_as_int(v), __float_as_int(v), 0x138, 0xf, 0xf, false));
}
__device__ __forceinline__ float dpp_right(float v) {  // lane i <- lane i+1 (wave_shl:1)
    return __int_as_float(__builtin_amdgcn_update_dpp(
        __float_as_int(v), __float_as_int(v), 0x130, 0xf, 0xf, false));
}

// One fused stage: consumes C (= u_{j-1}[f+1]), bank OV (= u_{j-1}[f-1]),
// bank NV (= u_{j-1}[f]); produces u_j[f] into C, rotates OV <- old C.
// GEN=1 adds uniform activity gating + row-mirror patches (head/tail only).
#define STAGE(jj, OV, NV, GEN)                                               \
    {                                                                        \
        f32x4 Cn; bool pr = true;                                            \
        const int f = _r - (jj);                                             \
        bool act = true;                                                     \
        if (GEN) {                                                           \
            const int lo = max(ob - KF + (jj), 0);                           \
            const int hi = min(ob + RB - 1 + KF - (jj), IMG - 1);            \
            act = (f >= lo) && (f <= hi);                                    \
        }                                                                    \
        if (act) {                                                           \
            const f32x4 mid = NV;                                            \
            f32x4 vs;                                                        \
            if (GEN && f == 0)              vs = C + C;    /* u[-1]=u[1] */  \
            else if (GEN && f == IMG - 1)   vs = OV + OV;  /* u[N]=u[N-2] */ \
            else                            vs = OV + C;                     \
            float lf = dpp_left(mid.w);                                      \
            float rg = dpp_right(mid.x);                                     \
            if (is_cL) lf = mid.y;             /* col 0: mirror col 1 */     \
            if (is_cR) rg = mid.z;             /* col 1023: mirror 1022 */   \
            f32x2 hlo, hhi;                                                  \
            hlo.x = lf    + mid.y;  hlo.y = mid.x + mid.z;                   \
            hhi.x = mid.y + mid.w;  hhi.y = mid.z + rg;                      \
            Cn.lo = vs.lo * w01 + hlo * w10 + mid.lo * w11;                  \
            Cn.hi = vs.hi * w01 + hhi * w10 + mid.hi * w11;                  \
        } else { pr = false; Cn = C; }                                       \
        if (prod) { OV = C; }                                                \
        C = Cn; prod = GEN ? pr : true;                                      \
    }

// One pipeline advance at absolute input row rv. PF (p0/p1) holds row rv,
// reloaded with row rv+2. Bank names passed explicitly per stage.
#define STEPN(rv, PF, GEN, O0,N0,O1,N1,O2,N2,O3,N3,O4,N4,                    \
                           O5,N5,O6,N6,O7,N7,O8,N8,O9,N9)                    \
    do {                                                                     \
        const int _r = (rv);                                                 \
        f32x4 C = PF;                                                        \
        if (_r + 2 <= in_hi)                                                 \
            PF = *(const f32x4*)(lp + (size_t)(_r + 2) * IMG);               \
        bool prod = GEN ? (_r <= in_hi) : true;                              \
        STAGE(1,  O0, N0, GEN)                                               \
        STAGE(2,  O1, N1, GEN)                                               \
        STAGE(3,  O2, N2, GEN)                                               \
        STAGE(4,  O3, N3, GEN)                                               \
        STAGE(5,  O4, N4, GEN)                                               \
        STAGE(6,  O5, N5, GEN)                                               \
        STAGE(7,  O6, N6, GEN)                                               \
        STAGE(8,  O7, N7, GEN)                                               \
        STAGE(9,  O8, N8, GEN)                                               \
        STAGE(10, O9, N9, GEN)                                               \
        if ((!GEN || prod) && st_ok)                                         \
            *(f32x4*)(op + (size_t)(_r - KF) * IMG) = C;                     \
    } while (0)

#define STEP_E(rv, GEN) STEPN(rv, p0, GEN, a0,b0,a1,b1,a2,b2,a3,b3,a4,b4,    \
                                           a5,b5,a6,b6,a7,b7,a8,b8,a9,b9)
#define STEP_O(rv, GEN) STEPN(rv, p1, GEN, b0,a0,b1,a1,b2,a2,b3,a3,b4,a4,    \
                                           b5,a5,b6,a6,b7,a7,b8,a8,b9,a9)

__global__ __launch_bounds__(64, 3) void diff10(
    const float* __restrict__ src, float* __restrict__ dst,
    const float* __restrict__ wt)
{
    const int lane  = threadIdx.x;          // 64-thread block == one wave
    const int gw    = blockIdx.x;
    const int plane = gw / WPL;
    const int rem   = gw - plane * WPL;
    const int band  = rem / NSW;
    const int sw    = rem - band * NSW;

    const int ob  = band * RB;              // first output row of this band
    const int uc0 = sw * SW;                // first useful col of this swath
    const int c0  = uc0 - LPAD + 4 * lane;  // this lane's first col (may be <0)
    const int cld = min(max(c0, 0), IMG - 4); // clamped load col (garbage ok)

    const float* __restrict__ lp = src + (size_t)plane * IMG * IMG + cld;
    float* __restrict__       op = dst + (size_t)plane * IMG * IMG + cld;

    const float* w9 = wt + (size_t)(plane & 1) * 9;
    const float w01 = w9[1];   // vertical weight (== w9[7])
    const float w10 = w9[3];   // horizontal weight (== w9[5])
    const float w11 = w9[4];   // center weight (corners are 0)

    const bool is_cL  = (c0 == 0);          // lane's .x is image col 0
    const bool is_cR  = (c0 == IMG - 4);    // lane's .w is image col 1023
    const bool st_ok  = (c0 >= uc0) && (c0 < uc0 + SW) && (c0 <= IMG - 4);

    const int r_lo  = max(ob - KF, 0);
    const int in_hi = min(ob + RB - 1 + KF, IMG - 1);
    const int r_hi  = ob + RB - 1 + KF;     // last pipeline iteration
    const int head_end = r_lo + 2 * KF - 1; // generic head (2*KF steps, even)
    const int st_end   = min(r_hi, IMG - 1);// steady end; tail drains

    // 2-row banks for stages u_0..u_9 — NAMED registers (never an array).
    f32x4 a0=0,a1=0,a2=0,a3=0,a4=0,a5=0,a6=0,a7=0,a8=0,a9=0;
    f32x4 b0=0,b1=0,b2=0,b3=0,b4=0,b5=0,b6=0,b7=0,b8=0,b9=0;

    f32x4 p0, p1;                           // distance-2 row prefetch slots
    p0 = *(const f32x4*)(lp + (size_t)r_lo * IMG);
    p1 = *(const f32x4*)(lp + (size_t)(r_lo + 1) * IMG);

    // Phase lengths are even and preserve the even/odd role alternation.
    // unroll(disable): bodies are already straight-line 10-stage blocks and
    // iterations are serially dependent — unrolling is pure code-size.
    #pragma clang loop unroll(disable)
    for (int r = r_lo; r <= head_end; r += 2) {
        STEP_E(r,     1);
        STEP_O(r + 1, 1);
    }
    #pragma clang loop unroll(disable)
    for (int r = head_end + 1; r <= st_end; r += 2) {
        STEP_E(r,     0);
        STEP_O(r + 1, 0);
    }
    #pragma clang loop unroll(disable)
    for (int r = st_end + 1; r <= r_hi; r += 2) {
        STEP_E(r,     1);
        STEP_O(r + 1, 1);
    }
}

extern "C" void kernel_launch(void* const* d_in, const int* in_sizes, int n_in,
                              void* d_out, int out_size, void* d_ws, size_t ws_size,
                              hipStream_t stream) {
    const float* x  = (const float*)d_in[0];
    const float* wt = (const float*)d_in[1];
    float* out = (float*)d_out;
    float* ws  = (float*)d_ws;   // needs >= 128 MiB (one tensor copy)

    dim3 g(NWAVES), b(64);
    // 20 steps = 2 launches x 10 fused steps
    diff10<<<g, b, 0, stream>>>(x,  ws,  wt);
    diff10<<<g, b, 0, stream>>>(ws, out, wt);
}